// Round 9
// baseline (201.881 us; speedup 1.0000x reference)
//
#include <hip/hip_runtime.h>

// Boundary_binaryLoss: 15x15 binary morphology boundary mask + masked NLL mean.
// B=32, C=2, H=480, W=864. logits [B,C,H,W] f32, labels [B,H,W] i32 in {0,1,255}.
//
// valid(b,h,w) = (label != 255) && (clipped 15x15 window has a px with
//   np_label==0 (label 0 or 255) AND a px with np_label==255 (label 1))
// loss = -sum(valid ? logits[b,label,h,w] : 0) / max(#valid, 1)
//
// R1..R8: atomics(66); sunk prefetch(66); lds-DMA(65); barrier-free scalar
//     (65); spill(91); fat fused(63); TH32 starved(103); block-coop(69).
// R9: R6 + XCD swizzle: FETCH 122->78MB (locality worked!) but dur 63.9.
//     Fabric theory dead. SURVIVING MODEL: R6/R9 both deliver ~1 L1-miss
//     line per ~8.6 cy per CU (292MB through L1 either way -- R9's halo
//     re-reads are L2-hits but still L1 MISSES). Warm replays identical =>
//     miss SOURCE irrelevant; per-CU miss-processing rate is the wall.
//     Lever: fewer L1-miss lines.
// R10: vertical register-walk. Wave = 216-col strip x 24 out rows, walked as
//     SEG=3 steps of TH=8; the 14-row halo's h-OR'd flags (28b) + center
//     bits ride in REGISTERS between steps (no re-read). Label halo
//     2.75x -> 1.58x: L1-miss ~292 -> ~203MB. 2560 waves (2.5/SIMD, above
//     R7's starvation), 4 consecutive segs per block (seam rows L2/L1-
//     local), XCD swizzle kept. Step body = R6's proven phases verbatim.
//     Predict: main -> 50-54us, WRITE ~60KB (spill tripwire), FETCH ~75MB.
//     If main stays 62-66: miss-rate theory falsified.
// R10b: round-8 bench died to infra ("container failed twice") -- no kernel
//     verdict. Re-audited bounds (all loads clamped in-image; bounded loops;
//     ws use 10KB) and pack algebra (22-row pack [y-7,y+15), fold bit 2o =
//     rows y+o-7..y+o+7, state shift keeps next halo exactly). Resubmitting
//     unchanged.

namespace {
constexpr int B_ = 32;
constexpr int H_ = 480;
constexpr int W_ = 864;
constexpr int HW = H_ * W_;
constexpr int R_ = 7;
constexpr int TH_ = 8;                    // rows per step
constexpr int SEG = 3;                    // steps per wave
constexpr int ORW = TH_ * SEG;            // 24 output rows per wave
constexpr int SW = 216;                   // output cols per strip
constexpr int NSX = W_ / SW;              // 4
constexpr int NSEG = H_ / ORW;            // 20 segments per column-strip
constexpr int WPB = 4;                    // waves/block = 4 consecutive segs
constexpr int NBLK = B_ * NSX * (NSEG / WPB);  // 32*4*5 = 640 (640%8==0)
} // namespace

typedef unsigned long long u64;

// Horizontal 15-OR across 4-px lanes (R6-proven). Payload: any <=28-bit pack
// of 2-bit rows. Garbage only reaches lanes outside [2,56) -> never consumed.
__device__ __forceinline__ void hwin15_4(unsigned f0, unsigned f1, unsigned f2,
                                         unsigned f3, unsigned& w0, unsigned& w1,
                                         unsigned& w2, unsigned& w3) {
  const unsigned allf = f0 | f1 | f2 | f3;
  const unsigned s2 = f2 | f3, s3 = f1 | s2;
  const unsigned p2 = f0 | f1, p3 = p2 | f2;
  const unsigned core = __shfl_up(allf, 1, 64) | allf | __shfl_down(allf, 1, 64);
  w0 = core | __shfl_up(s3, 2, 64);
  w1 = core | __shfl_up(s2, 2, 64) | __shfl_down(f0, 2, 64);
  w2 = core | __shfl_up(f3, 2, 64) | __shfl_down(p2, 2, 64);
  w3 = core | __shfl_down(p3, 2, 64);
}

extern "C" __global__ __launch_bounds__(256, 4)
void boundary_loss_main(const float* __restrict__ logits,
                        const int* __restrict__ labels,
                        double2* __restrict__ partials)
{
  __shared__ double red_s[WPB];
  __shared__ unsigned red_c[WPB];

  const int tid = threadIdx.x;
  const int lane = tid & 63;
  const int wv = tid >> 6;
  // XCD swizzle: XCD k owns lb in [80k,80k+80) = 4 whole images.
  const int lb = (blockIdx.x & 7) * (NBLK / 8) + (blockIdx.x >> 3);
  const int img = lb / 20;                 // 20 blocks per image
  const int r = lb - img * 20;
  const int strip = r / 5;                 // 0..3
  const int segblk = r - strip * 5;        // 0..4
  const int seg = segblk * WPB + wv;       // 0..19; block = 4 consecutive segs
  const int gr0 = seg * ORW;               // first output row of the walk

  const int cb0 = strip * SW - 8 + 4 * lane;          // lane's 4-col base
  const bool colinb = (cb0 >= 0) && (cb0 + 3 < W_);
  const int cbc = colinb ? cb0 : (cb0 < 0 ? 0 : W_ - 4);
  const bool labok = colinb && (lane < 58);
  const bool outl = (lane >= 2) && (lane < 56);       // 54 lanes x 4 = 216

  const int* __restrict__ lab = labels + img * HW + cbc;
  const float* __restrict__ lg = logits + (size_t)(2 * img) * HW;
  const float* pg = lg + (size_t)gr0 * W_ + cb0;      // only deref'd if outl

  // ---- prologue: rows [gr0-7, gr0+7) -> carried state (14 rows) ----
  // Wst[j]: 28 bits of h-OR'd flags (bit0 np==0, bit1 np==255, 2b/row)
  // Cst[j]: 28 bits raw center (bit0 label==1, bit1 ignore, 2b/row)
  unsigned pf0 = 0, pf1 = 0, pf2 = 0, pf3 = 0;
  u64 Cst0 = 0, Cst1 = 0, Cst2 = 0, Cst3 = 0;
#pragma unroll
  for (int a = 0; a < 14; ++a) {
    const int gr = gr0 - R_ + a;           // max gr0+6 = 462 < H_, only top clip
    const int grc = gr < 0 ? 0 : gr;
    const int4 v = *(const int4*)(lab + grc * W_);
    const unsigned m = (labok && gr >= 0) ? 3u : 0u;
    const int sh = 2 * a;
    pf0 |= (((v.x == 1) ? 2u : 1u) & m) << sh;
    pf1 |= (((v.y == 1) ? 2u : 1u) & m) << sh;
    pf2 |= (((v.z == 1) ? 2u : 1u) & m) << sh;
    pf3 |= (((v.w == 1) ? 2u : 1u) & m) << sh;
    Cst0 |= (u64)(((v.x == 1) ? 1u : 0u) | ((v.x == 255) ? 2u : 0u)) << sh;
    Cst1 |= (u64)(((v.y == 1) ? 1u : 0u) | ((v.y == 255) ? 2u : 0u)) << sh;
    Cst2 |= (u64)(((v.z == 1) ? 1u : 0u) | ((v.z == 255) ? 2u : 0u)) << sh;
    Cst3 |= (u64)(((v.w == 1) ? 1u : 0u) | ((v.w == 255) ? 2u : 0u)) << sh;
  }
  unsigned Wst0, Wst1, Wst2, Wst3;
  hwin15_4(pf0, pf1, pf2, pf3, Wst0, Wst1, Wst2, Wst3);

  double lsum = 0.0;
  unsigned lcnt = 0;

  // ---- walk: SEG steps of 8 output rows ----
  for (int s = 0; s < SEG; ++s) {
    const int y = gr0 + s * TH_;

    // (a) issue logits for rows [y, y+8) -- latency hides under label phase
    float4 g0[TH_], g1[TH_];
    if (outl) {
      const float* p_ = pg + (size_t)(s * TH_) * W_;
#pragma unroll
      for (int o = 0; o < TH_; ++o) {
        g0[o] = *(const float4*)(p_ + (size_t)o * W_);
        g1[o] = *(const float4*)(p_ + (size_t)o * W_ + HW);
      }
    }

    // (b) load + fold 8 NEW label rows [y+7, y+15)
    unsigned nf0 = 0, nf1 = 0, nf2 = 0, nf3 = 0;
    u64 nc0 = 0, nc1 = 0, nc2 = 0, nc3 = 0;
#pragma unroll
    for (int k = 0; k < TH_; ++k) {
      const int gr = y + R_ + k;           // >= 7, may exceed bottom
      const int grc = gr >= H_ ? H_ - 1 : gr;
      const int4 v = *(const int4*)(lab + grc * W_);
      const unsigned m = (labok && gr < H_) ? 3u : 0u;
      const int sh = 2 * k;
      nf0 |= (((v.x == 1) ? 2u : 1u) & m) << sh;
      nf1 |= (((v.y == 1) ? 2u : 1u) & m) << sh;
      nf2 |= (((v.z == 1) ? 2u : 1u) & m) << sh;
      nf3 |= (((v.w == 1) ? 2u : 1u) & m) << sh;
      nc0 |= (u64)(((v.x == 1) ? 1u : 0u) | ((v.x == 255) ? 2u : 0u)) << sh;
      nc1 |= (u64)(((v.y == 1) ? 1u : 0u) | ((v.y == 255) ? 2u : 0u)) << sh;
      nc2 |= (u64)(((v.z == 1) ? 1u : 0u) | ((v.z == 255) ? 2u : 0u)) << sh;
      nc3 |= (u64)(((v.w == 1) ? 1u : 0u) | ((v.w == 255) ? 2u : 0u)) << sh;
    }

    // (c) h-OR the new rows, append to carried state: 44-bit combined pack,
    //     bit 2i <-> label row y-7+i
    unsigned nw0, nw1, nw2, nw3;
    hwin15_4(nf0, nf1, nf2, nf3, nw0, nw1, nw2, nw3);
    const u64 F0 = (u64)Wst0 | ((u64)nw0 << 28);
    const u64 F1 = (u64)Wst1 | ((u64)nw1 << 28);
    const u64 F2 = (u64)Wst2 | ((u64)nw2 << 28);
    const u64 F3 = (u64)Wst3 | ((u64)nw3 << 28);
    const u64 Cc0 = Cst0 | (nc0 << 28);
    const u64 Cc1 = Cst1 | (nc1 << 28);
    const u64 Cc2 = Cst2 | (nc2 << 28);
    const u64 Cc3 = Cst3 | (nc3 << 28);

    // (d) vertical 15-OR: bit 2o := OR bits 2o..2(o+14)  (o = 0..7)
    u64 V0 = F0, V1 = F1, V2 = F2, V3 = F3;
    V0 |= V0 >> 2;  V0 |= V0 >> 4;  V0 |= V0 >> 8;  V0 |= V0 >> 14;
    V1 |= V1 >> 2;  V1 |= V1 >> 4;  V1 |= V1 >> 8;  V1 |= V1 >> 14;
    V2 |= V2 >> 2;  V2 |= V2 >> 4;  V2 |= V2 >> 8;  V2 |= V2 >> 14;
    V3 |= V3 >> 2;  V3 |= V3 >> 4;  V3 |= V3 >> 8;  V3 |= V3 >> 14;

    // (e) select + accumulate; out row y+o is combined-pack position o+7
    if (outl) {
#pragma unroll
      for (int o = 0; o < TH_; ++o) {
        const unsigned b0 = (unsigned)(V0 >> (2 * o)) & 3u;
        const unsigned b1 = (unsigned)(V1 >> (2 * o)) & 3u;
        const unsigned b2 = (unsigned)(V2 >> (2 * o)) & 3u;
        const unsigned b3 = (unsigned)(V3 >> (2 * o)) & 3u;
        const unsigned q0 = (unsigned)(Cc0 >> (14 + 2 * o)) & 3u;
        const unsigned q1 = (unsigned)(Cc1 >> (14 + 2 * o)) & 3u;
        const unsigned q2 = (unsigned)(Cc2 >> (14 + 2 * o)) & 3u;
        const unsigned q3 = (unsigned)(Cc3 >> (14 + 2 * o)) & 3u;
        const float4 a = g0[o], c = g1[o];
        const bool k0 = (b0 == 3u) && !(q0 & 2u);
        const bool k1 = (b1 == 3u) && !(q1 & 2u);
        const bool k2 = (b2 == 3u) && !(q2 & 2u);
        const bool k3 = (b3 == 3u) && !(q3 & 2u);
        lsum += k0 ? (double)((q0 & 1u) ? c.x : a.x) : 0.0;
        lsum += k1 ? (double)((q1 & 1u) ? c.y : a.y) : 0.0;
        lsum += k2 ? (double)((q2 & 1u) ? c.z : a.z) : 0.0;
        lsum += k3 ? (double)((q3 & 1u) ? c.w : a.w) : 0.0;
        lcnt += (unsigned)k0 + k1 + k2 + k3;
      }
    }

    // (f) shift state down 8 rows: keep rows [y+1, y+15)
    Wst0 = (unsigned)(F0 >> 16) & 0x0FFFFFFFu;
    Wst1 = (unsigned)(F1 >> 16) & 0x0FFFFFFFu;
    Wst2 = (unsigned)(F2 >> 16) & 0x0FFFFFFFu;
    Wst3 = (unsigned)(F3 >> 16) & 0x0FFFFFFFu;
    Cst0 = (Cc0 >> 16) & 0x0FFFFFFFull;
    Cst1 = (Cc1 >> 16) & 0x0FFFFFFFull;
    Cst2 = (Cc2 >> 16) & 0x0FFFFFFFull;
    Cst3 = (Cc3 >> 16) & 0x0FFFFFFFull;
  }

  // ---- wave + block reduction -> one double2 per block ----
#pragma unroll
  for (int off = 32; off > 0; off >>= 1) {
    lsum += __shfl_down(lsum, off, 64);
    lcnt += __shfl_down(lcnt, off, 64);
  }
  if ((tid & 63) == 0) { red_s[wv] = lsum; red_c[wv] = lcnt; }
  __syncthreads();                         // tail-only
  if (tid == 0) {
    const double s = red_s[0] + red_s[1] + red_s[2] + red_s[3];
    const double c = (double)(red_c[0] + red_c[1] + red_c[2] + red_c[3]);
    partials[blockIdx.x] = make_double2(s, c);
  }
}

extern "C" __global__ __launch_bounds__(1024)
void boundary_loss_final(const double2* __restrict__ partials,
                         float* __restrict__ out)
{
  __shared__ double red_s[16];
  __shared__ double red_c[16];
  const int tid = threadIdx.x;
  double s = 0.0, c = 0.0;
  for (int i = tid; i < NBLK; i += 1024) {
    const double2 p = partials[i];
    s += p.x;
    c += p.y;
  }
#pragma unroll
  for (int off = 32; off > 0; off >>= 1) {
    s += __shfl_down(s, off, 64);
    c += __shfl_down(c, off, 64);
  }
  const int wave = tid >> 6;
  if ((tid & 63) == 0) { red_s[wave] = s; red_c[wave] = c; }
  __syncthreads();
  if (tid == 0) {
    double ts = 0.0, tc = 0.0;
#pragma unroll
    for (int i = 0; i < 16; ++i) { ts += red_s[i]; tc += red_c[i]; }
    if (tc < 1.0) tc = 1.0;
    out[0] = (float)(-ts / tc);
  }
}

extern "C" void kernel_launch(void* const* d_in, const int* in_sizes, int n_in,
                              void* d_out, int out_size, void* d_ws, size_t ws_size,
                              hipStream_t stream)
{
  const float* logits = (const float*)d_in[0];
  const int* labels = (const int*)d_in[1];
  float* out = (float*)d_out;
  double2* partials = (double2*)d_ws;  // NBLK*16 B = 10,240 B; every slot
                                       // written by main -> no init needed.

  boundary_loss_main<<<dim3(NBLK), 256, 0, stream>>>(logits, labels, partials);
  boundary_loss_final<<<1, 1024, 0, stream>>>(partials, out);
}